// Round 2
// baseline (147.186 us; speedup 1.0000x reference)
//
#include <hip/hip_runtime.h>
#include <hip/hip_bf16.h>

#define S_SRC 4096
#define DIM 128
#define BATCH 2

typedef unsigned short u16;
typedef __bf16 bf16x8 __attribute__((ext_vector_type(8)));
typedef float f32x4 __attribute__((ext_vector_type(4)));

__device__ __forceinline__ __bf16 bf_hi(float x) { return (__bf16)x; }
__device__ __forceinline__ __bf16 bf_lo(float x, __bf16 h) { return (__bf16)(x - (float)h); }
__device__ __forceinline__ u16 bfu(__bf16 h) { return __builtin_bit_cast(u16, h); }
__device__ __forceinline__ u16 f2bu(float x) { return __builtin_bit_cast(u16, (__bf16)x); }

// ---------------- kernel 0: transpose + hi/lo split the weight matrices ----------------
// wt layout: [mat][hl][e][d]  (e = output col, d = input dim) -> B-frag reads contiguous
__global__ __launch_bounds__(256) void k_wsplit(const float* __restrict__ wq,
                                                const float* __restrict__ wk,
                                                const float* __restrict__ wv,
                                                u16* __restrict__ wt) {
  int idx = blockIdx.x * 256 + threadIdx.x;  // 3*128*128 = 49152
  int mat = idx >> 14;
  int r = idx & 16383;
  int d = r >> 7, e = r & 127;
  const float* w = (mat == 0) ? wq : ((mat == 1) ? wk : wv);
  float x = w[r];
  if (mat == 0) x *= 0.08838834764831845f;  // fold 1/sqrt(128) into Wq
  __bf16 h = bf_hi(x);
  __bf16 l = bf_lo(x, h);
  wt[((mat * 2 + 0) * 128 + e) * 128 + d] = bfu(h);
  wt[((mat * 2 + 1) * 128 + e) * 128 + d] = bfu(l);
}

// ---------------- kernel 1: QKV projection (bf16 hi/lo, 3-product MFMA) ----------------
__global__ __launch_bounds__(256) void k_proj(const float* __restrict__ X,
                                              const u16* __restrict__ wt,
                                              u16* __restrict__ Qh, u16* __restrict__ Ql,
                                              u16* __restrict__ Kh, u16* __restrict__ Kl,
                                              u16* __restrict__ VT) {
  const int b = blockIdx.x >> 7;
  const int tile = blockIdx.x & 127;
  const int tid = threadIdx.x;
  const int w = tid >> 6, lane = tid & 63, g = lane >> 4, l16 = lane & 15;

  // A-frags: X rows (fp32 -> hi/lo bf16)
  bf16x8 a_h[2][4], a_l[2][4];
#pragma unroll
  for (int mf = 0; mf < 2; ++mf) {
    int row = tile * 32 + mf * 16 + l16;
    const float* xr = X + ((size_t)b * S_SRC + row) * DIM;
#pragma unroll
    for (int kf = 0; kf < 4; ++kf) {
      int d0 = kf * 32 + g * 8;
      f32x4 x0 = *(const f32x4*)(xr + d0);
      f32x4 x1 = *(const f32x4*)(xr + d0 + 4);
#pragma unroll
      for (int j = 0; j < 4; ++j) {
        __bf16 h0 = bf_hi(x0[j]);
        __bf16 h1 = bf_hi(x1[j]);
        a_h[mf][kf][j] = h0;
        a_l[mf][kf][j] = bf_lo(x0[j], h0);
        a_h[mf][kf][4 + j] = h1;
        a_l[mf][kf][4 + j] = bf_lo(x1[j], h1);
      }
    }
  }

#pragma unroll
  for (int mat = 0; mat < 3; ++mat) {
    const u16* wth = wt + (mat * 2 + 0) * 16384;
    const u16* wtl = wt + (mat * 2 + 1) * 16384;
#pragma unroll
    for (int nf = 0; nf < 2; ++nf) {
      int col = w * 32 + nf * 16 + l16;
      f32x4 acc[2];
      acc[0] = (f32x4){0.f, 0.f, 0.f, 0.f};
      acc[1] = (f32x4){0.f, 0.f, 0.f, 0.f};
#pragma unroll
      for (int kf = 0; kf < 4; ++kf) {
        int d0 = kf * 32 + g * 8;
        bf16x8 bh = *(const bf16x8*)(const void*)(wth + col * 128 + d0);
        bf16x8 bl = *(const bf16x8*)(const void*)(wtl + col * 128 + d0);
#pragma unroll
        for (int mf = 0; mf < 2; ++mf) {
          acc[mf] = __builtin_amdgcn_mfma_f32_16x16x32_bf16(a_h[mf][kf], bh, acc[mf], 0, 0, 0);
          acc[mf] = __builtin_amdgcn_mfma_f32_16x16x32_bf16(a_h[mf][kf], bl, acc[mf], 0, 0, 0);
          acc[mf] = __builtin_amdgcn_mfma_f32_16x16x32_bf16(a_l[mf][kf], bh, acc[mf], 0, 0, 0);
        }
      }
#pragma unroll
      for (int mf = 0; mf < 2; ++mf)
#pragma unroll
        for (int r = 0; r < 4; ++r) {
          int row = tile * 32 + mf * 16 + g * 4 + r;
          float v = acc[mf][r];
          if (mat == 2) {
            VT[((size_t)b * DIM + col) * S_SRC + row] = f2bu(v);
          } else {
            __bf16 h = bf_hi(v);
            __bf16 l = bf_lo(v, h);
            size_t o = ((size_t)b * S_SRC + row) * DIM + col;
            if (mat == 0) { Qh[o] = bfu(h); Ql[o] = bfu(l); }
            else          { Kh[o] = bfu(h); Kl[o] = bfu(l); }
          }
        }
    }
  }
}

// ---------------- kernel 2: flash attention (wave-split KV, end-combine) ----------------
__global__ __launch_bounds__(256) void k_attn(const u16* __restrict__ Qh, const u16* __restrict__ Ql,
                                              const u16* __restrict__ Kh, const u16* __restrict__ Kl,
                                              const u16* __restrict__ VT, float* __restrict__ out) {
  const int b = blockIdx.x >> 7;
  const int tile = blockIdx.x & 127;
  const int tid = threadIdx.x;
  const int w = tid >> 6, lane = tid & 63, g = lane >> 4, l16 = lane & 15;

  __shared__ alignas(16) u16 p_lds[4][32][32];
  __shared__ alignas(16) float O_s[32][DIM];
  __shared__ float m_s[32], l_s[32];

  // Q fragments (hi/lo) for rows tile*32 .. +31
  bf16x8 q_h[2][4], q_l[2][4];
#pragma unroll
  for (int mf = 0; mf < 2; ++mf) {
    int row = tile * 32 + mf * 16 + l16;
    const u16* qph = Qh + ((size_t)b * S_SRC + row) * DIM;
    const u16* qpl = Ql + ((size_t)b * S_SRC + row) * DIM;
#pragma unroll
    for (int kf = 0; kf < 4; ++kf) {
      int d0 = kf * 32 + g * 8;
      q_h[mf][kf] = *(const bf16x8*)(const void*)(qph + d0);
      q_l[mf][kf] = *(const bf16x8*)(const void*)(qpl + d0);
    }
  }

  f32x4 acc[2][8];
#pragma unroll
  for (int mf = 0; mf < 2; ++mf)
#pragma unroll
    for (int nf = 0; nf < 8; ++nf) acc[mf][nf] = (f32x4){0.f, 0.f, 0.f, 0.f};
  float m_run[2][4], l_run[2][4];
#pragma unroll
  for (int mf = 0; mf < 2; ++mf)
#pragma unroll
    for (int r = 0; r < 4; ++r) { m_run[mf][r] = -1e30f; l_run[mf][r] = 0.f; }

  for (int t = w; t < S_SRC / 32; t += 4) {
    const int key0 = t * 32;
    // ---- scores: S = Q Khat^T (3-product hi/lo) ----
    f32x4 sacc[2][2];
#pragma unroll
    for (int mf = 0; mf < 2; ++mf) {
      sacc[mf][0] = (f32x4){0.f, 0.f, 0.f, 0.f};
      sacc[mf][1] = (f32x4){0.f, 0.f, 0.f, 0.f};
    }
#pragma unroll
    for (int nf = 0; nf < 2; ++nf) {
      const u16* kbh = Kh + ((size_t)b * S_SRC + key0 + nf * 16 + l16) * DIM;
      const u16* kbl = Kl + ((size_t)b * S_SRC + key0 + nf * 16 + l16) * DIM;
#pragma unroll
      for (int kf = 0; kf < 4; ++kf) {
        int d0 = kf * 32 + g * 8;
        bf16x8 kh = *(const bf16x8*)(const void*)(kbh + d0);
        bf16x8 kl = *(const bf16x8*)(const void*)(kbl + d0);
#pragma unroll
        for (int mf = 0; mf < 2; ++mf) {
          sacc[mf][nf] = __builtin_amdgcn_mfma_f32_16x16x32_bf16(q_h[mf][kf], kh, sacc[mf][nf], 0, 0, 0);
          sacc[mf][nf] = __builtin_amdgcn_mfma_f32_16x16x32_bf16(q_h[mf][kf], kl, sacc[mf][nf], 0, 0, 0);
          sacc[mf][nf] = __builtin_amdgcn_mfma_f32_16x16x32_bf16(q_l[mf][kf], kh, sacc[mf][nf], 0, 0, 0);
        }
      }
    }
    // ---- online softmax (rows live across 16-lane groups) ----
#pragma unroll
    for (int mf = 0; mf < 2; ++mf) {
      float fac[4];
#pragma unroll
      for (int r = 0; r < 4; ++r) {
        float s0 = sacc[mf][0][r], s1 = sacc[mf][1][r];
        float v = fmaxf(s0, s1);
        v = fmaxf(v, __shfl_xor(v, 1, 64));
        v = fmaxf(v, __shfl_xor(v, 2, 64));
        v = fmaxf(v, __shfl_xor(v, 4, 64));
        v = fmaxf(v, __shfl_xor(v, 8, 64));
        float mo = m_run[mf][r];
        float mn = fmaxf(mo, v);
        float f = __expf(mo - mn);
        fac[r] = f;
        float p0 = __expf(s0 - mn);
        float p1 = __expf(s1 - mn);
        float sm = p0 + p1;
        sm += __shfl_xor(sm, 1, 64);
        sm += __shfl_xor(sm, 2, 64);
        sm += __shfl_xor(sm, 4, 64);
        sm += __shfl_xor(sm, 8, 64);
        l_run[mf][r] = l_run[mf][r] * f + sm;
        m_run[mf][r] = mn;
        int row = mf * 16 + g * 4 + r;
        p_lds[w][row][l16] = f2bu(p0);
        p_lds[w][row][16 + l16] = f2bu(p1);
      }
#pragma unroll
      for (int nf = 0; nf < 8; ++nf)
#pragma unroll
        for (int r = 0; r < 4; ++r) acc[mf][nf][r] *= fac[r];
    }
    // wave-private LDS bounce: C-frag layout -> A-frag layout
    asm volatile("s_waitcnt lgkmcnt(0)" ::: "memory");
    bf16x8 pa[2];
#pragma unroll
    for (int mf = 0; mf < 2; ++mf)
      pa[mf] = *(const bf16x8*)(const void*)(&p_lds[w][mf * 16 + l16][g * 8]);
    // ---- PV: O += P * V  (V^T layout -> contiguous B-frags) ----
#pragma unroll
    for (int nf = 0; nf < 8; ++nf) {
      int dcol = nf * 16 + l16;
      bf16x8 vf = *(const bf16x8*)(const void*)(VT + ((size_t)b * DIM + dcol) * S_SRC + key0 + g * 8);
#pragma unroll
      for (int mf = 0; mf < 2; ++mf)
        acc[mf][nf] = __builtin_amdgcn_mfma_f32_16x16x32_bf16(pa[mf], vf, acc[mf][nf], 0, 0, 0);
    }
  }

  // ---- cross-wave combine (sequential merge, barrier-ordered) ----
  for (int wv = 0; wv < 4; ++wv) {
    if (w == wv) {
#pragma unroll
      for (int mf = 0; mf < 2; ++mf)
#pragma unroll
        for (int r = 0; r < 4; ++r) {
          int row = mf * 16 + g * 4 + r;
          if (wv == 0) {
            if (l16 == 0) { m_s[row] = m_run[mf][r]; l_s[row] = l_run[mf][r]; }
#pragma unroll
            for (int nf = 0; nf < 8; ++nf) O_s[row][nf * 16 + l16] = acc[mf][nf][r];
          } else {
            float mo = m_s[row];
            float mw = m_run[mf][r];
            float mn = fmaxf(mo, mw);
            float fo = __expf(mo - mn);
            float fw = __expf(mw - mn);
#pragma unroll
            for (int nf = 0; nf < 8; ++nf) {
              int c = nf * 16 + l16;
              O_s[row][c] = O_s[row][c] * fo + acc[mf][nf][r] * fw;
            }
            if (l16 == 0) { l_s[row] = l_s[row] * fo + l_run[mf][r] * fw; m_s[row] = mn; }
          }
        }
    }
    __syncthreads();
  }

  float* op = out + ((size_t)b * S_SRC + tile * 32) * DIM;
  for (int i = tid; i < 32 * DIM; i += 256) {
    int row = i >> 7;
    op[i] = O_s[row][i & 127] / l_s[row];
  }
}

extern "C" void kernel_launch(void* const* d_in, const int* in_sizes, int n_in,
                              void* d_out, int out_size, void* d_ws, size_t ws_size,
                              hipStream_t stream) {
  const float* X  = (const float*)d_in[0];
  const float* wq = (const float*)d_in[4];
  const float* wk = (const float*)d_in[5];
  const float* wv = (const float*)d_in[6];
  float* out = (float*)d_out;

  u16* WT = (u16*)d_ws;                       // 3*2*128*128 u16 = 192 KiB
  u16* Qh = WT + 3 * 2 * 128 * 128;
  u16* Ql = Qh + (size_t)BATCH * S_SRC * DIM; // 2 MiB each
  u16* Kh = Ql + (size_t)BATCH * S_SRC * DIM;
  u16* Kl = Kh + (size_t)BATCH * S_SRC * DIM;
  u16* VT = Kl + (size_t)BATCH * S_SRC * DIM; // [B][D][S]

  hipLaunchKernelGGL(k_wsplit, dim3(192), dim3(256), 0, stream, wq, wk, wv, WT);
  hipLaunchKernelGGL(k_proj, dim3(BATCH * S_SRC / 32), dim3(256), 0, stream,
                     X, WT, Qh, Ql, Kh, Kl, VT);
  hipLaunchKernelGGL(k_attn, dim3(BATCH * S_SRC / 32), dim3(256), 0, stream,
                     Qh, Ql, Kh, Kl, VT, out);
}